// Round 3
// baseline (245.636 us; speedup 1.0000x reference)
//
#include <hip/hip_runtime.h>
#include <math.h>

#define NB 8
#define NC 256
#define NL 4096
#define NK 65
#define PADL 32

// Per-batch stats in a device global (always valid, no d_ws dependency).
// [b][0..3] = sum_re, sum_im, sum_sq, inv_std
__device__ float g_stats[NB * 4];

__global__ void zero_stats_kernel() {
    if (threadIdx.x < NB * 4) g_stats[threadIdx.x] = 0.0f;
}

// ---------------------------------------------------------------------------
// Kernel 1: conv stats ONLY (no conv output stored anywhere).
// y[b,c,l] = sum_j x[b,c,l+j-32]*(kre[j] - i*kim[j]); accumulate per-batch
// sum_re, sum_im, sum_|y|^2. One block per (row, half of L).
// ---------------------------------------------------------------------------
__global__ __launch_bounds__(256) void conv_stats_kernel(
    const float* __restrict__ x,
    const float* __restrict__ kre,
    const float* __restrict__ kim)
{
    __shared__ __align__(16) float xs[2112];   // 2048 + 64 halo
    __shared__ float skr[NK], ski[NK];
    __shared__ float red[12];

    const int t = threadIdx.x;
    const int bid = blockIdx.x;
    const int r = bid >> 1;                 // row = b*NC + c
    const int base_l = (bid & 1) << 11;     // 0 or 2048
    const int b = r >> 8;

    const float* xrow = x + (size_t)r * NL;
    for (int i = t; i < 2112; i += 256) {
        int gl = base_l + i - PADL;
        xs[i] = (gl >= 0 && gl < NL) ? xrow[gl] : 0.0f;
    }
    if (t < NK) { skr[t] = kre[t]; ski[t] = kim[t]; }
    __syncthreads();

    float w[72];
    const float4* xs4 = (const float4*)xs;
    #pragma unroll
    for (int q = 0; q < 18; ++q) {
        float4 v = xs4[2*t + q];
        w[4*q+0] = v.x; w[4*q+1] = v.y; w[4*q+2] = v.z; w[4*q+3] = v.w;
    }

    float accr[8], acci[8];
    #pragma unroll
    for (int i = 0; i < 8; ++i) { accr[i] = 0.0f; acci[i] = 0.0f; }

    #pragma unroll
    for (int j = 0; j < NK; ++j) {
        const float kr = skr[j];
        const float ki = ski[j];
        #pragma unroll
        for (int i = 0; i < 8; ++i) {
            accr[i] = fmaf(w[i+j], kr, accr[i]);
            acci[i] = fmaf(w[i+j], ki, acci[i]);
        }
    }

    float sr = 0.0f, si = 0.0f, sq = 0.0f;
    #pragma unroll
    for (int i = 0; i < 8; ++i) {
        sr += accr[i];
        si -= acci[i];                      // im = -acci
        sq = fmaf(accr[i], accr[i], sq);
        sq = fmaf(acci[i], acci[i], sq);
    }
    #pragma unroll
    for (int off = 32; off > 0; off >>= 1) {
        sr += __shfl_down(sr, off);
        si += __shfl_down(si, off);
        sq += __shfl_down(sq, off);
    }
    const int lane = t & 63, wv = t >> 6;
    if (lane == 0) { red[wv*3+0] = sr; red[wv*3+1] = si; red[wv*3+2] = sq; }
    __syncthreads();
    if (t == 0) {
        float a0 = 0.0f, a1 = 0.0f, a2 = 0.0f;
        for (int i = 0; i < 4; ++i) { a0 += red[i*3]; a1 += red[i*3+1]; a2 += red[i*3+2]; }
        atomicAdd(&g_stats[b*4+0], a0);
        atomicAdd(&g_stats[b*4+1], a1);
        atomicAdd(&g_stats[b*4+2], a2);
    }
}

// ---------------------------------------------------------------------------
// Kernel 2: inv_std[b] = rsqrt( (sum|y|^2 - |sum y|^2 / n) / (n-1) )
// ---------------------------------------------------------------------------
__global__ void finalize_stats_kernel()
{
    int b = threadIdx.x;
    if (b < NB) {
        float sr = g_stats[b*4+0], si = g_stats[b*4+1], sq = g_stats[b*4+2];
        const float n = (float)(NC * NL);
        float var = (sq - (sr*sr + si*si)/n) / (n - 1.0f);
        g_stats[b*4+3] = rsqrtf(var);
    }
}

// ---------------------------------------------------------------------------
// Kernel 3: fused conv-recompute + normalize + weight + 256-pt FFT over
// channels + fftshift. Block = (batch, 16-wide l-tile), thread = channel.
// Writes ONLY to d_out, layout selected by out_size, every store guarded.
// ---------------------------------------------------------------------------
__global__ __launch_bounds__(256) void fused_fft_kernel(
    const float* __restrict__ x,
    const float* __restrict__ kre,
    const float* __restrict__ kim,
    const float* __restrict__ wmag,
    const float* __restrict__ wang,
    float* __restrict__ out,
    int out_size)
{
    __shared__ __align__(16) float buf[NC * 36];  // [c] rows, stride 9 float4 (pad)
    __shared__ float twr[NC], twi[NC];
    __shared__ float skr[NK], ski[NK];

    const int t = threadIdx.x;      // channel
    const int bid = blockIdx.x;
    const int b = bid >> 8;
    const int tile = bid & 255;
    const int l0 = tile << 4;

    {
        float ang = (float)t * 0.024543692606170260f;  // 2*pi/256
        float s, c;
        sincosf(ang, &s, &c);
        twr[t] = c; twi[t] = -s;
    }
    if (t < NK) { skr[t] = kre[t]; ski[t] = kim[t]; }
    const float inv = g_stats[b*4+3];
    float sw, cw;
    sincosf(wang[t], &sw, &cw);
    const float wm = wmag[t];
    const float wgr = inv * wm * cw;     // inv * wm * cos(wa)
    const float wgi = -inv * wm * sw;    // -inv * wm * sin(wa)
    __syncthreads();

    // ---- conv recompute: 16 outputs for channel t from an 80-float window
    float w[80];
    const float* xrow = x + (size_t)(b * NC + t) * NL;
    const int base = l0 - PADL;          // -32 .. 4048, multiple of 16
    if (base >= 0 && base + 80 <= NL) {
        const float4* xr4 = (const float4*)(xrow + base);
        #pragma unroll
        for (int q = 0; q < 20; ++q) {
            float4 v = xr4[q];
            w[4*q+0] = v.x; w[4*q+1] = v.y; w[4*q+2] = v.z; w[4*q+3] = v.w;
        }
    } else {
        #pragma unroll
        for (int i = 0; i < 80; ++i) {
            int gl = base + i;
            w[i] = (gl >= 0 && gl < NL) ? xrow[gl] : 0.0f;
        }
    }

    float sr[16], si[16];
    #pragma unroll
    for (int i = 0; i < 16; ++i) { sr[i] = 0.0f; si[i] = 0.0f; }
    #pragma unroll
    for (int j = 0; j < NK; ++j) {
        const float kr = skr[j];
        const float ki = ski[j];
        #pragma unroll
        for (int i = 0; i < 16; ++i) {
            sr[i] = fmaf(w[i+j], kr, sr[i]);
            si[i] = fmaf(w[i+j], ki, si[i]);
        }
    }
    // y = (sr, -si);  y' = y * (wgr + i*wgi):
    // re = sr*wgr + si*wgi ; im = sr*wgi - si*wgr

    float4* lbuf4 = (float4*)buf;
    #pragma unroll
    for (int k = 0; k < 8; ++k) {
        float4 o;
        o.x = sr[2*k]   * wgr + si[2*k]   * wgi;
        o.y = sr[2*k]   * wgi - si[2*k]   * wgr;
        o.z = sr[2*k+1] * wgr + si[2*k+1] * wgi;
        o.w = sr[2*k+1] * wgi - si[2*k+1] * wgr;
        lbuf4[t*9 + k] = o;
    }
    __syncthreads();

    // ---- 4 radix-4 DIF stages over channels (row stride 9 float4)
    #pragma unroll
    for (int s = 0; s < 4; ++s) {
        const int shift = 2 * s;
        const int q = 64 >> shift;
        #pragma unroll
        for (int it = 0; it < 2; ++it) {
            int task = it * 256 + t;       // 512 tasks = 64 butterflies x 8 lpairs
            int lpp = task & 7;
            int m = task >> 3;
            int j = m & (q - 1);
            int blk = m >> (6 - shift);
            int base2 = blk << (8 - shift);
            int e = j << shift;            // 3e <= 189 < 256

            int ca = base2 + j;
            float4 a0 = lbuf4[ca*9 + lpp];
            float4 a1 = lbuf4[(ca + q)*9 + lpp];
            float4 a2 = lbuf4[(ca + 2*q)*9 + lpp];
            float4 a3 = lbuf4[(ca + 3*q)*9 + lpp];

            float w1r = twr[e],   w1i = twi[e];
            float w2r = twr[2*e], w2i = twi[2*e];
            float w3r = twr[3*e], w3i = twi[3*e];

            float4 b0, b1, b2, b3;
            {
                float t0r = a0.x + a2.x, t0i = a0.y + a2.y;
                float t1r = a0.x - a2.x, t1i = a0.y - a2.y;
                float t2r = a1.x + a3.x, t2i = a1.y + a3.y;
                float t3r = a1.x - a3.x, t3i = a1.y - a3.y;
                b0.x = t0r + t2r;       b0.y = t0i + t2i;
                float b2r = t0r - t2r,  b2i = t0i - t2i;
                float b1r = t1r + t3i,  b1i = t1i - t3r;
                float b3r = t1r - t3i,  b3i = t1i + t3r;
                b1.x = b1r*w1r - b1i*w1i;  b1.y = b1r*w1i + b1i*w1r;
                b2.x = b2r*w2r - b2i*w2i;  b2.y = b2r*w2i + b2i*w2r;
                b3.x = b3r*w3r - b3i*w3i;  b3.y = b3r*w3i + b3i*w3r;
            }
            {
                float t0r = a0.z + a2.z, t0i = a0.w + a2.w;
                float t1r = a0.z - a2.z, t1i = a0.w - a2.w;
                float t2r = a1.z + a3.z, t2i = a1.w + a3.w;
                float t3r = a1.z - a3.z, t3i = a1.w - a3.w;
                b0.z = t0r + t2r;       b0.w = t0i + t2i;
                float b2r = t0r - t2r,  b2i = t0i - t2i;
                float b1r = t1r + t3i,  b1i = t1i - t3r;
                float b3r = t1r - t3i,  b3i = t1i + t3r;
                b1.z = b1r*w1r - b1i*w1i;  b1.w = b1r*w1i + b1i*w1r;
                b2.z = b2r*w2r - b2i*w2i;  b2.w = b2r*w2i + b2i*w2r;
                b3.z = b3r*w3r - b3i*w3i;  b3.w = b3r*w3i + b3i*w3r;
            }
            lbuf4[ca*9 + lpp]         = b0;
            lbuf4[(ca + q)*9 + lpp]   = b1;
            lbuf4[(ca + 2*q)*9 + lpp] = b2;
            lbuf4[(ca + 3*q)*9 + lpp] = b3;
        }
        __syncthreads();
    }

    // ---- store: digit-reverse + fftshift; layout chosen by out_size
    const bool interleaved = (out_size >= 2 * NB * NC * NL);
    #pragma unroll
    for (int it = 0; it < 8; ++it) {
        int task = it * 256 + t;
        int lpp = task & 7;
        int p = task >> 3;
        float4 v = lbuf4[p*9 + lpp];
        int k = ((p & 3) << 6) | (((p >> 2) & 3) << 4)
              | (((p >> 4) & 3) << 2) | ((p >> 6) & 3);
        int cout = k ^ 128;  // fftshift
        if (interleaved) {
            // interleaved complex floats: [b][cout][2*l .. 2*l+1]
            size_t fi = 2 * ((size_t)(b * NC + cout) * NL + l0) + 4 * lpp;
            if (fi + 4 <= (size_t)out_size) *(float4*)(out + fi) = v;
        } else {
            // real part only: [b][cout][l]
            size_t fi = (size_t)(b * NC + cout) * NL + l0 + 2 * lpp;
            if (fi + 2 <= (size_t)out_size) {
                float2 o2; o2.x = v.x; o2.y = v.z;
                *(float2*)(out + fi) = o2;
            }
        }
    }
}

extern "C" void kernel_launch(void* const* d_in, const int* in_sizes, int n_in,
                              void* d_out, int out_size, void* d_ws, size_t ws_size,
                              hipStream_t stream)
{
    const float* x   = (const float*)d_in[0];
    const float* kre = (const float*)d_in[1];
    const float* kim = (const float*)d_in[2];
    const float* wm  = (const float*)d_in[3];
    const float* wa  = (const float*)d_in[4];
    float* out = (float*)d_out;
    (void)d_ws; (void)ws_size;

    zero_stats_kernel<<<1, 64, 0, stream>>>();
    conv_stats_kernel<<<NB * NC * 2, 256, 0, stream>>>(x, kre, kim);
    finalize_stats_kernel<<<1, 64, 0, stream>>>();
    fused_fft_kernel<<<NB * (NL / 16), 256, 0, stream>>>(x, kre, kim, wm, wa,
                                                         out, out_size);
}

// Round 4
// 209.469 us; speedup vs baseline: 1.1727x; 1.1727x over previous
//
#include <hip/hip_runtime.h>
#include <math.h>

#define NB 8
#define NC 256
#define NL 4096
#define NK 65

// Per-batch stats in a device global. [b][0..3] = sum_re, sum_im, sum_sq, inv_std
__device__ float g_stats[NB * 4];

__global__ void zero_stats_kernel() {
    if (threadIdx.x < NB * 4) g_stats[threadIdx.x] = 0.0f;
}

// XOR swizzle on float4 index: spreads lane-stride-4 b128 reads evenly over
// all 8 bank-quads (permutation within each 8-float4 block).
__device__ __forceinline__ int swz(int a) { return a ^ ((a >> 3) & 7); }

// ---------------------------------------------------------------------------
// Kernel 1: conv stats only. One block per row, 256 threads x 16 outputs.
// Taps chunked 4x16+1 so the 32-float window chunk stays in VGPRs
// (round-3 failure: 72-float window was demoted -> 520 ds_read_b32/thread).
// Taps read via uniform s_load (scalar cache), not LDS.
// ---------------------------------------------------------------------------
__global__ __launch_bounds__(256) void conv_stats_kernel(
    const float* __restrict__ x,
    const float* __restrict__ kre,
    const float* __restrict__ kim)
{
    __shared__ __align__(16) float4 xs4[1040];  // words 4a-32 .. 4a-29, swizzled
    __shared__ float red[12];

    const int t = threadIdx.x;
    const int r = blockIdx.x;               // row = b*NC + c
    const int b = r >> 8;
    const float* xrow = x + (size_t)r * NL;

    // stage row + 32-word halo each side (a = 0..1039)
    #pragma unroll
    for (int it = 0; it < 5; ++it) {
        int a = it * 256 + t;
        if (a < 1040) {
            float4 v;
            if (a >= 8 && a <= 1031) {
                v = *(const float4*)(xrow + 4 * a - 32);
            } else {
                float e0, e1, e2, e3;
                int g0 = 4 * a - 32;
                e0 = (g0 + 0 >= 0 && g0 + 0 < NL) ? xrow[g0 + 0] : 0.0f;
                e1 = (g0 + 1 >= 0 && g0 + 1 < NL) ? xrow[g0 + 1] : 0.0f;
                e2 = (g0 + 2 >= 0 && g0 + 2 < NL) ? xrow[g0 + 2] : 0.0f;
                e3 = (g0 + 3 >= 0 && g0 + 3 < NL) ? xrow[g0 + 3] : 0.0f;
                v = make_float4(e0, e1, e2, e3);
            }
            xs4[swz(a)] = v;
        }
    }
    __syncthreads();

    float sr[16], si[16];
    #pragma unroll
    for (int i = 0; i < 16; ++i) { sr[i] = 0.0f; si[i] = 0.0f; }

    const int a0 = 4 * t;   // window word_base for chunk cb = 16t - 32 + 16cb
                            // -> float4 index a0 + 4*cb + q
    #pragma unroll
    for (int cb = 0; cb < 4; ++cb) {
        float w[32];
        #pragma unroll
        for (int q = 0; q < 8; ++q) {
            float4 v = xs4[swz(a0 + 4 * cb + q)];
            w[4*q+0] = v.x; w[4*q+1] = v.y; w[4*q+2] = v.z; w[4*q+3] = v.w;
        }
        #pragma unroll
        for (int j2 = 0; j2 < 16; ++j2) {
            const float kr = kre[16 * cb + j2];   // uniform -> s_load
            const float ki = kim[16 * cb + j2];
            #pragma unroll
            for (int i = 0; i < 16; ++i) {
                sr[i] = fmaf(w[i + j2], kr, sr[i]);
                si[i] = fmaf(w[i + j2], ki, si[i]);
            }
        }
    }
    // tail tap j = 64: words 16t+32 .. 16t+47 -> a = 4t+16+q
    {
        float w[16];
        #pragma unroll
        for (int q = 0; q < 4; ++q) {
            float4 v = xs4[swz(a0 + 16 + q)];
            w[4*q+0] = v.x; w[4*q+1] = v.y; w[4*q+2] = v.z; w[4*q+3] = v.w;
        }
        const float kr = kre[64];
        const float ki = kim[64];
        #pragma unroll
        for (int i = 0; i < 16; ++i) {
            sr[i] = fmaf(w[i], kr, sr[i]);
            si[i] = fmaf(w[i], ki, si[i]);
        }
    }

    // stats: y = (sr, -si)
    float ssr = 0.0f, ssi = 0.0f, ssq = 0.0f;
    #pragma unroll
    for (int i = 0; i < 16; ++i) {
        ssr += sr[i];
        ssi -= si[i];
        ssq = fmaf(sr[i], sr[i], ssq);
        ssq = fmaf(si[i], si[i], ssq);
    }
    #pragma unroll
    for (int off = 32; off > 0; off >>= 1) {
        ssr += __shfl_down(ssr, off);
        ssi += __shfl_down(ssi, off);
        ssq += __shfl_down(ssq, off);
    }
    const int lane = t & 63, wv = t >> 6;
    if (lane == 0) { red[wv*3+0] = ssr; red[wv*3+1] = ssi; red[wv*3+2] = ssq; }
    __syncthreads();
    if (t == 0) {
        float a0s = 0.0f, a1s = 0.0f, a2s = 0.0f;
        for (int i = 0; i < 4; ++i) { a0s += red[i*3]; a1s += red[i*3+1]; a2s += red[i*3+2]; }
        atomicAdd(&g_stats[b*4+0], a0s);
        atomicAdd(&g_stats[b*4+1], a1s);
        atomicAdd(&g_stats[b*4+2], a2s);
    }
}

// ---------------------------------------------------------------------------
// Kernel 2: inv_std[b] = rsqrt( (sum|y|^2 - |sum y|^2 / n) / (n-1) )
// ---------------------------------------------------------------------------
__global__ void finalize_stats_kernel()
{
    int b = threadIdx.x;
    if (b < NB) {
        float sr = g_stats[b*4+0], si = g_stats[b*4+1], sq = g_stats[b*4+2];
        const float n = (float)(NC * NL);
        float var = (sq - (sr*sr + si*si)/n) / (n - 1.0f);
        g_stats[b*4+3] = rsqrtf(var);
    }
}

// ---------------------------------------------------------------------------
// Kernel 3: fused conv-recompute + normalize + weight + 256-pt FFT + fftshift.
// Block = (batch, 16-wide l-tile), thread = channel. Conv windows staged
// per-tap-chunk through LDS with COALESCED global reads (round-3 version
// issued 64-line uncoalesced per-lane loads); the same 36 KB buffer is then
// reused for the radix-4 FFT.
// ---------------------------------------------------------------------------
__global__ __launch_bounds__(256) void fused_fft_kernel(
    const float* __restrict__ x,
    const float* __restrict__ kre,
    const float* __restrict__ kim,
    const float* __restrict__ wmag,
    const float* __restrict__ wang,
    float* __restrict__ out,
    int out_size)
{
    __shared__ __align__(16) float4 lbuf4[NC * 9];  // 36 KB: staging, then FFT
    __shared__ float twr[NC], twi[NC];

    const int t = threadIdx.x;      // channel
    const int bid = blockIdx.x;
    const int b = bid >> 8;
    const int l0 = (bid & 255) << 4;

    {
        float ang = (float)t * 0.024543692606170260f;  // 2*pi/256
        float s, c;
        sincosf(ang, &s, &c);
        twr[t] = c; twi[t] = -s;
    }
    const float inv = g_stats[b*4+3];
    float sw, cw;
    sincosf(wang[t], &sw, &cw);
    const float wm = wmag[t];
    const float wgr = inv * wm * cw;
    const float wgi = -inv * wm * sw;

    const float* xb = x + (size_t)b * NC * NL;

    float sr[16], si[16];
    #pragma unroll
    for (int i = 0; i < 16; ++i) { sr[i] = 0.0f; si[i] = 0.0f; }

    #pragma unroll
    for (int cb = 0; cb < 4; ++cb) {
        __syncthreads();   // previous chunk's reads (and twiddle init) done
        // stage 256 rows x 32 words, coalesced
        #pragma unroll
        for (int it = 0; it < 8; ++it) {
            int fidx = it * 256 + t;
            int rr = fidx >> 3, q = fidx & 7;
            int g0 = l0 + 16 * cb - 32 + 4 * q;
            const float* xr = xb + (size_t)rr * NL;
            float4 v;
            if (g0 >= 0 && g0 <= NL - 4) {
                v = *(const float4*)(xr + g0);
            } else {
                float e0 = (g0 + 0 >= 0 && g0 + 0 < NL) ? xr[g0 + 0] : 0.0f;
                float e1 = (g0 + 1 >= 0 && g0 + 1 < NL) ? xr[g0 + 1] : 0.0f;
                float e2 = (g0 + 2 >= 0 && g0 + 2 < NL) ? xr[g0 + 2] : 0.0f;
                float e3 = (g0 + 3 >= 0 && g0 + 3 < NL) ? xr[g0 + 3] : 0.0f;
                v = make_float4(e0, e1, e2, e3);
            }
            lbuf4[rr * 9 + q] = v;
        }
        __syncthreads();
        float w[32];
        #pragma unroll
        for (int q = 0; q < 8; ++q) {
            float4 v = lbuf4[t * 9 + q];   // quad = (t+q)&7: even spread
            w[4*q+0] = v.x; w[4*q+1] = v.y; w[4*q+2] = v.z; w[4*q+3] = v.w;
        }
        #pragma unroll
        for (int j2 = 0; j2 < 16; ++j2) {
            const float kr = kre[16 * cb + j2];
            const float ki = kim[16 * cb + j2];
            #pragma unroll
            for (int i = 0; i < 16; ++i) {
                sr[i] = fmaf(w[i + j2], kr, sr[i]);
                si[i] = fmaf(w[i + j2], ki, si[i]);
            }
        }
    }
    // tail tap j = 64: words l0+32 .. l0+47 per row
    __syncthreads();
    #pragma unroll
    for (int it = 0; it < 4; ++it) {
        int fidx = it * 256 + t;
        int rr = fidx >> 2, q = fidx & 3;
        int g0 = l0 + 32 + 4 * q;
        const float* xr = xb + (size_t)rr * NL;
        float4 v;
        if (g0 <= NL - 4) {
            v = *(const float4*)(xr + g0);
        } else {
            float e0 = (g0 + 0 < NL) ? xr[g0 + 0] : 0.0f;
            float e1 = (g0 + 1 < NL) ? xr[g0 + 1] : 0.0f;
            float e2 = (g0 + 2 < NL) ? xr[g0 + 2] : 0.0f;
            float e3 = (g0 + 3 < NL) ? xr[g0 + 3] : 0.0f;
            v = make_float4(e0, e1, e2, e3);
        }
        lbuf4[rr * 9 + q] = v;
    }
    __syncthreads();
    {
        float w[16];
        #pragma unroll
        for (int q = 0; q < 4; ++q) {
            float4 v = lbuf4[t * 9 + q];
            w[4*q+0] = v.x; w[4*q+1] = v.y; w[4*q+2] = v.z; w[4*q+3] = v.w;
        }
        const float kr = kre[64];
        const float ki = kim[64];
        #pragma unroll
        for (int i = 0; i < 16; ++i) {
            sr[i] = fmaf(w[i], kr, sr[i]);
            si[i] = fmaf(w[i], ki, si[i]);
        }
    }

    // y = (sr, -si); y' = y * (wgr + i*wgi)  ->  re = sr*wgr + si*wgi,
    // im = sr*wgi - si*wgr. Write into own FFT row (no cross-thread hazard:
    // tail reads above were also own-row only).
    #pragma unroll
    for (int k = 0; k < 8; ++k) {
        float4 o;
        o.x = sr[2*k]   * wgr + si[2*k]   * wgi;
        o.y = sr[2*k]   * wgi - si[2*k]   * wgr;
        o.z = sr[2*k+1] * wgr + si[2*k+1] * wgi;
        o.w = sr[2*k+1] * wgi - si[2*k+1] * wgr;
        lbuf4[t * 9 + k] = o;
    }
    __syncthreads();

    // ---- 4 radix-4 DIF stages over channels (row stride 9 float4)
    #pragma unroll
    for (int s = 0; s < 4; ++s) {
        const int shift = 2 * s;
        const int q = 64 >> shift;
        #pragma unroll
        for (int it = 0; it < 2; ++it) {
            int task = it * 256 + t;       // 512 tasks = 64 butterflies x 8 lpairs
            int lpp = task & 7;
            int m = task >> 3;
            int j = m & (q - 1);
            int blk = m >> (6 - shift);
            int base2 = blk << (8 - shift);
            int e = j << shift;            // 3e <= 189 < 256

            int ca = base2 + j;
            float4 a0 = lbuf4[ca*9 + lpp];
            float4 a1 = lbuf4[(ca + q)*9 + lpp];
            float4 a2 = lbuf4[(ca + 2*q)*9 + lpp];
            float4 a3 = lbuf4[(ca + 3*q)*9 + lpp];

            float w1r = twr[e],   w1i = twi[e];
            float w2r = twr[2*e], w2i = twi[2*e];
            float w3r = twr[3*e], w3i = twi[3*e];

            float4 b0, b1, b2, b3;
            {
                float t0r = a0.x + a2.x, t0i = a0.y + a2.y;
                float t1r = a0.x - a2.x, t1i = a0.y - a2.y;
                float t2r = a1.x + a3.x, t2i = a1.y + a3.y;
                float t3r = a1.x - a3.x, t3i = a1.y - a3.y;
                b0.x = t0r + t2r;       b0.y = t0i + t2i;
                float b2r = t0r - t2r,  b2i = t0i - t2i;
                float b1r = t1r + t3i,  b1i = t1i - t3r;
                float b3r = t1r - t3i,  b3i = t1i + t3r;
                b1.x = b1r*w1r - b1i*w1i;  b1.y = b1r*w1i + b1i*w1r;
                b2.x = b2r*w2r - b2i*w2i;  b2.y = b2r*w2i + b2i*w2r;
                b3.x = b3r*w3r - b3i*w3i;  b3.y = b3r*w3i + b3i*w3r;
            }
            {
                float t0r = a0.z + a2.z, t0i = a0.w + a2.w;
                float t1r = a0.z - a2.z, t1i = a0.w - a2.w;
                float t2r = a1.z + a3.z, t2i = a1.w + a3.w;
                float t3r = a1.z - a3.z, t3i = a1.w - a3.w;
                b0.z = t0r + t2r;       b0.w = t0i + t2i;
                float b2r = t0r - t2r,  b2i = t0i - t2i;
                float b1r = t1r + t3i,  b1i = t1i - t3r;
                float b3r = t1r - t3i,  b3i = t1i + t3r;
                b1.z = b1r*w1r - b1i*w1i;  b1.w = b1r*w1i + b1i*w1r;
                b2.z = b2r*w2r - b2i*w2i;  b2.w = b2r*w2i + b2i*w2r;
                b3.z = b3r*w3r - b3i*w3i;  b3.w = b3r*w3i + b3i*w3r;
            }
            lbuf4[ca*9 + lpp]         = b0;
            lbuf4[(ca + q)*9 + lpp]   = b1;
            lbuf4[(ca + 2*q)*9 + lpp] = b2;
            lbuf4[(ca + 3*q)*9 + lpp] = b3;
        }
        __syncthreads();
    }

    // ---- store: digit-reverse + fftshift; layout chosen by out_size
    const bool interleaved = (out_size >= 2 * NB * NC * NL);
    #pragma unroll
    for (int it = 0; it < 8; ++it) {
        int task = it * 256 + t;
        int lpp = task & 7;
        int p = task >> 3;
        float4 v = lbuf4[p*9 + lpp];
        int k = ((p & 3) << 6) | (((p >> 2) & 3) << 4)
              | (((p >> 4) & 3) << 2) | ((p >> 6) & 3);
        int cout = k ^ 128;  // fftshift
        if (interleaved) {
            size_t fi = 2 * ((size_t)(b * NC + cout) * NL + l0) + 4 * lpp;
            if (fi + 4 <= (size_t)out_size) *(float4*)(out + fi) = v;
        } else {
            size_t fi = (size_t)(b * NC + cout) * NL + l0 + 2 * lpp;
            if (fi + 2 <= (size_t)out_size) {
                float2 o2; o2.x = v.x; o2.y = v.z;
                *(float2*)(out + fi) = o2;
            }
        }
    }
}

extern "C" void kernel_launch(void* const* d_in, const int* in_sizes, int n_in,
                              void* d_out, int out_size, void* d_ws, size_t ws_size,
                              hipStream_t stream)
{
    const float* x   = (const float*)d_in[0];
    const float* kre = (const float*)d_in[1];
    const float* kim = (const float*)d_in[2];
    const float* wm  = (const float*)d_in[3];
    const float* wa  = (const float*)d_in[4];
    float* out = (float*)d_out;
    (void)d_ws; (void)ws_size;

    zero_stats_kernel<<<1, 64, 0, stream>>>();
    conv_stats_kernel<<<NB * NC, 256, 0, stream>>>(x, kre, kim);
    finalize_stats_kernel<<<1, 64, 0, stream>>>();
    fused_fft_kernel<<<NB * (NL / 16), 256, 0, stream>>>(x, kre, kim, wm, wa,
                                                         out, out_size);
}

// Round 5
// 203.827 us; speedup vs baseline: 1.2051x; 1.0277x over previous
//
#include <hip/hip_runtime.h>
#include <math.h>

#define NB 8
#define NC 256
#define NL 4096
#define NK 65

// Per-batch stats in a device global. [b][0..3] = sum_re, sum_im, sum_sq, inv_std
__device__ float g_stats[NB * 4];

__global__ void zero_stats_kernel() {
    if (threadIdx.x < NB * 4) g_stats[threadIdx.x] = 0.0f;
}

// ---------------------------------------------------------------------------
// Kernel 2: inv_std[b] = rsqrt( (sum|y|^2 - |sum y|^2 / n) / (n-1) )
// ---------------------------------------------------------------------------
__global__ void finalize_stats_kernel()
{
    int b = threadIdx.x;
    if (b < NB) {
        float sr = g_stats[b*4+0], si = g_stats[b*4+1], sq = g_stats[b*4+2];
        const float n = (float)(NC * NL);
        float var = (sq - (sr*sr + si*si)/n) / (n - 1.0f);
        g_stats[b*4+3] = rsqrtf(var);
    }
}

// ---------------------------------------------------------------------------
// Kernel 1 (fused): conv + stats-accumulate + weight (NO inv_std; it is a
// per-batch real scalar and FFT/weight/fftshift are linear, so it is applied
// post-hoc by scale_out_kernel) + 256-pt FFT over channels + fftshift.
//
// Block = strip of 2 consecutive 16-wide l-tiles (halo overfetch 5x -> 1.5x
// within a block). XCD swizzle p=(bid&7)*128+(bid>>3) puts each batch
// (4 MB of x = one XCD's L2) on one XCD so inter-strip halo re-reads hit L2
// (round-4: FETCH 151 MB vs 32 MB ideal because adjacent tiles were on
// different, non-coherent XCD L2s).
// ---------------------------------------------------------------------------
__global__ __launch_bounds__(256) void fused_conv_fft_kernel(
    const float* __restrict__ x,
    const float* __restrict__ kre,
    const float* __restrict__ kim,
    const float* __restrict__ wmag,
    const float* __restrict__ wang,
    float* __restrict__ out,
    int out_size)
{
    __shared__ __align__(16) float4 lbuf4[NC * 9];  // 36 KB: staging, then FFT
    __shared__ float twr[NC], twi[NC];
    __shared__ float red[12];

    const int t = threadIdx.x;      // channel
    const int p = ((blockIdx.x & 7) << 7) | (blockIdx.x >> 3);  // XCD swizzle
    const int b = p >> 7;           // batch = XCD (8 batches, 8 XCDs)
    const int L0 = (p & 127) << 5;  // strip base: 128 strips x 32 l per batch

    {
        float ang = (float)t * 0.024543692606170260f;  // 2*pi/256
        float s, c;
        sincosf(ang, &s, &c);
        twr[t] = c; twi[t] = -s;
    }
    float sw, cw;
    sincosf(wang[t], &sw, &cw);
    const float wm = wmag[t];
    const float wgr =  wm * cw;     // weight WITHOUT inv_std
    const float wgi = -wm * sw;

    const float* xb = x + (size_t)b * NC * NL;
    const bool interleaved = (out_size >= 2 * NB * NC * NL);

    float tsr = 0.0f, tsi = 0.0f, tsq = 0.0f;   // per-thread stats over strip

    for (int it2 = 0; it2 < 2; ++it2) {
        const int l0 = L0 + (it2 << 4);

        float sr[16], si[16];
        #pragma unroll
        for (int i = 0; i < 16; ++i) { sr[i] = 0.0f; si[i] = 0.0f; }

        #pragma unroll
        for (int cb = 0; cb < 4; ++cb) {
            __syncthreads();   // prior tile's lbuf4 reads / twiddle init done
            // stage 256 rows x 32 words, coalesced
            #pragma unroll
            for (int it = 0; it < 8; ++it) {
                int fidx = it * 256 + t;
                int rr = fidx >> 3, q = fidx & 7;
                int g0 = l0 + 16 * cb - 32 + 4 * q;
                const float* xr = xb + (size_t)rr * NL;
                float4 v;
                if (g0 >= 0 && g0 <= NL - 4) {
                    v = *(const float4*)(xr + g0);
                } else {
                    float e0 = (g0 + 0 >= 0 && g0 + 0 < NL) ? xr[g0 + 0] : 0.0f;
                    float e1 = (g0 + 1 >= 0 && g0 + 1 < NL) ? xr[g0 + 1] : 0.0f;
                    float e2 = (g0 + 2 >= 0 && g0 + 2 < NL) ? xr[g0 + 2] : 0.0f;
                    float e3 = (g0 + 3 >= 0 && g0 + 3 < NL) ? xr[g0 + 3] : 0.0f;
                    v = make_float4(e0, e1, e2, e3);
                }
                lbuf4[rr * 9 + q] = v;
            }
            __syncthreads();
            float w[32];
            #pragma unroll
            for (int q = 0; q < 8; ++q) {
                float4 v = lbuf4[t * 9 + q];   // quad=(t+q)&7: even bank spread
                w[4*q+0] = v.x; w[4*q+1] = v.y; w[4*q+2] = v.z; w[4*q+3] = v.w;
            }
            #pragma unroll
            for (int j2 = 0; j2 < 16; ++j2) {
                const float kr = kre[16 * cb + j2];   // uniform -> s_load
                const float ki = kim[16 * cb + j2];
                #pragma unroll
                for (int i = 0; i < 16; ++i) {
                    sr[i] = fmaf(w[i + j2], kr, sr[i]);
                    si[i] = fmaf(w[i + j2], ki, si[i]);
                }
            }
        }
        // tail tap j = 64: words l0+32 .. l0+47 per row
        __syncthreads();
        #pragma unroll
        for (int it = 0; it < 4; ++it) {
            int fidx = it * 256 + t;
            int rr = fidx >> 2, q = fidx & 3;
            int g0 = l0 + 32 + 4 * q;
            const float* xr = xb + (size_t)rr * NL;
            float4 v;
            if (g0 <= NL - 4) {
                v = *(const float4*)(xr + g0);
            } else {
                float e0 = (g0 + 0 < NL) ? xr[g0 + 0] : 0.0f;
                float e1 = (g0 + 1 < NL) ? xr[g0 + 1] : 0.0f;
                float e2 = (g0 + 2 < NL) ? xr[g0 + 2] : 0.0f;
                float e3 = (g0 + 3 < NL) ? xr[g0 + 3] : 0.0f;
                v = make_float4(e0, e1, e2, e3);
            }
            lbuf4[rr * 9 + q] = v;
        }
        __syncthreads();
        {
            float w[16];
            #pragma unroll
            for (int q = 0; q < 4; ++q) {
                float4 v = lbuf4[t * 9 + q];
                w[4*q+0] = v.x; w[4*q+1] = v.y; w[4*q+2] = v.z; w[4*q+3] = v.w;
            }
            const float kr = kre[64];
            const float ki = kim[64];
            #pragma unroll
            for (int i = 0; i < 16; ++i) {
                sr[i] = fmaf(w[i], kr, sr[i]);
                si[i] = fmaf(w[i], ki, si[i]);
            }
        }

        // stats on y = (sr, -si), un-normalized
        #pragma unroll
        for (int i = 0; i < 16; ++i) {
            tsr += sr[i];
            tsi -= si[i];
            tsq = fmaf(sr[i], sr[i], tsq);
            tsq = fmaf(si[i], si[i], tsq);
        }

        // y' = y * (wgr + i*wgi): re = sr*wgr + si*wgi, im = sr*wgi - si*wgr.
        // Own-row write; tail reads above were own-row only -> no hazard.
        #pragma unroll
        for (int k = 0; k < 8; ++k) {
            float4 o;
            o.x = sr[2*k]   * wgr + si[2*k]   * wgi;
            o.y = sr[2*k]   * wgi - si[2*k]   * wgr;
            o.z = sr[2*k+1] * wgr + si[2*k+1] * wgi;
            o.w = sr[2*k+1] * wgi - si[2*k+1] * wgr;
            lbuf4[t * 9 + k] = o;
        }
        __syncthreads();

        // ---- 4 radix-4 DIF stages over channels (row stride 9 float4)
        #pragma unroll
        for (int s = 0; s < 4; ++s) {
            const int shift = 2 * s;
            const int q = 64 >> shift;
            #pragma unroll
            for (int it = 0; it < 2; ++it) {
                int task = it * 256 + t;   // 512 tasks = 64 butterflies x 8 lpairs
                int lpp = task & 7;
                int m = task >> 3;
                int j = m & (q - 1);
                int blk = m >> (6 - shift);
                int base2 = blk << (8 - shift);
                int e = j << shift;        // 3e <= 189 < 256

                int ca = base2 + j;
                float4 a0 = lbuf4[ca*9 + lpp];
                float4 a1 = lbuf4[(ca + q)*9 + lpp];
                float4 a2 = lbuf4[(ca + 2*q)*9 + lpp];
                float4 a3 = lbuf4[(ca + 3*q)*9 + lpp];

                float w1r = twr[e],   w1i = twi[e];
                float w2r = twr[2*e], w2i = twi[2*e];
                float w3r = twr[3*e], w3i = twi[3*e];

                float4 b0, b1, b2, b3;
                {
                    float t0r = a0.x + a2.x, t0i = a0.y + a2.y;
                    float t1r = a0.x - a2.x, t1i = a0.y - a2.y;
                    float t2r = a1.x + a3.x, t2i = a1.y + a3.y;
                    float t3r = a1.x - a3.x, t3i = a1.y - a3.y;
                    b0.x = t0r + t2r;       b0.y = t0i + t2i;
                    float b2r = t0r - t2r,  b2i = t0i - t2i;
                    float b1r = t1r + t3i,  b1i = t1i - t3r;
                    float b3r = t1r - t3i,  b3i = t1i + t3r;
                    b1.x = b1r*w1r - b1i*w1i;  b1.y = b1r*w1i + b1i*w1r;
                    b2.x = b2r*w2r - b2i*w2i;  b2.y = b2r*w2i + b2i*w2r;
                    b3.x = b3r*w3r - b3i*w3i;  b3.y = b3r*w3i + b3i*w3r;
                }
                {
                    float t0r = a0.z + a2.z, t0i = a0.w + a2.w;
                    float t1r = a0.z - a2.z, t1i = a0.w - a2.w;
                    float t2r = a1.z + a3.z, t2i = a1.w + a3.w;
                    float t3r = a1.z - a3.z, t3i = a1.w - a3.w;
                    b0.z = t0r + t2r;       b0.w = t0i + t2i;
                    float b2r = t0r - t2r,  b2i = t0i - t2i;
                    float b1r = t1r + t3i,  b1i = t1i - t3r;
                    float b3r = t1r - t3i,  b3i = t1i + t3r;
                    b1.z = b1r*w1r - b1i*w1i;  b1.w = b1r*w1i + b1i*w1r;
                    b2.z = b2r*w2r - b2i*w2i;  b2.w = b2r*w2i + b2i*w2r;
                    b3.z = b3r*w3r - b3i*w3i;  b3.w = b3r*w3i + b3i*w3r;
                }
                lbuf4[ca*9 + lpp]         = b0;
                lbuf4[(ca + q)*9 + lpp]   = b1;
                lbuf4[(ca + 2*q)*9 + lpp] = b2;
                lbuf4[(ca + 3*q)*9 + lpp] = b3;
            }
            __syncthreads();
        }

        // ---- store (un-normalized): digit-reverse + fftshift
        #pragma unroll
        for (int it = 0; it < 8; ++it) {
            int task = it * 256 + t;
            int lpp = task & 7;
            int pp = task >> 3;
            float4 v = lbuf4[pp*9 + lpp];
            int k = ((pp & 3) << 6) | (((pp >> 2) & 3) << 4)
                  | (((pp >> 4) & 3) << 2) | ((pp >> 6) & 3);
            int cout = k ^ 128;  // fftshift
            if (interleaved) {
                size_t fi = 2 * ((size_t)(b * NC + cout) * NL + l0) + 4 * lpp;
                if (fi + 4 <= (size_t)out_size) *(float4*)(out + fi) = v;
            } else {
                size_t fi = (size_t)(b * NC + cout) * NL + l0 + 2 * lpp;
                if (fi + 2 <= (size_t)out_size) {
                    float2 o2; o2.x = v.x; o2.y = v.z;
                    *(float2*)(out + fi) = o2;
                }
            }
        }
    }

    // ---- strip stats -> per-batch atomics
    #pragma unroll
    for (int off = 32; off > 0; off >>= 1) {
        tsr += __shfl_down(tsr, off);
        tsi += __shfl_down(tsi, off);
        tsq += __shfl_down(tsq, off);
    }
    const int lane = t & 63, wv = t >> 6;
    __syncthreads();   // store loop's lbuf4 reads done before red reuse is moot, but order red writes
    if (lane == 0) { red[wv*3+0] = tsr; red[wv*3+1] = tsi; red[wv*3+2] = tsq; }
    __syncthreads();
    if (t == 0) {
        float a0 = 0.0f, a1 = 0.0f, a2 = 0.0f;
        for (int i = 0; i < 4; ++i) { a0 += red[i*3]; a1 += red[i*3+1]; a2 += red[i*3+2]; }
        atomicAdd(&g_stats[b*4+0], a0);
        atomicAdd(&g_stats[b*4+1], a1);
        atomicAdd(&g_stats[b*4+2], a2);
    }
}

// ---------------------------------------------------------------------------
// Kernel 3: out *= inv_std[b]. Both output layouts are [b][...], so
// b = flat_idx / (out_size/NB). float4 main loop + scalar tail.
// ---------------------------------------------------------------------------
__global__ __launch_bounds__(256) void scale_out_kernel(
    float* __restrict__ out, int out_size)
{
    const int chunk = out_size >> 3;           // floats per batch (NB=8)
    const int n4 = out_size >> 2;
    float4* o4 = (float4*)out;
    for (int i4 = blockIdx.x * blockDim.x + threadIdx.x; i4 < n4;
         i4 += gridDim.x * blockDim.x) {
        int b = (i4 << 2) / chunk;
        float inv = g_stats[b*4+3];
        float4 v = o4[i4];
        v.x *= inv; v.y *= inv; v.z *= inv; v.w *= inv;
        o4[i4] = v;
    }
    // tail (out_size not multiple of 4)
    int tail0 = n4 << 2;
    int ti = tail0 + blockIdx.x * blockDim.x + threadIdx.x;
    if (ti < out_size) {
        int b = ti / chunk;
        out[ti] *= g_stats[b*4+3];
    }
}

extern "C" void kernel_launch(void* const* d_in, const int* in_sizes, int n_in,
                              void* d_out, int out_size, void* d_ws, size_t ws_size,
                              hipStream_t stream)
{
    const float* x   = (const float*)d_in[0];
    const float* kre = (const float*)d_in[1];
    const float* kim = (const float*)d_in[2];
    const float* wm  = (const float*)d_in[3];
    const float* wa  = (const float*)d_in[4];
    float* out = (float*)d_out;
    (void)d_ws; (void)ws_size;

    zero_stats_kernel<<<1, 64, 0, stream>>>();
    fused_conv_fft_kernel<<<NB * (NL / 32), 256, 0, stream>>>(x, kre, kim, wm, wa,
                                                              out, out_size);
    finalize_stats_kernel<<<1, 64, 0, stream>>>();
    scale_out_kernel<<<2048, 256, 0, stream>>>(out, out_size);
}

// Round 6
// 181.144 us; speedup vs baseline: 1.3560x; 1.1252x over previous
//
#include <hip/hip_runtime.h>
#include <math.h>

#define NB 8
#define NC 256
#define NL 4096
#define NK 65

// Per-batch stats. [b][0..3] = sum_re, sum_im, sum_sq, inv_std
__device__ float g_stats[NB * 4];

__global__ void zero_stats_kernel() {
    if (threadIdx.x < NB * 4) g_stats[threadIdx.x] = 0.0f;
}

__global__ void finalize_stats_kernel()
{
    int b = threadIdx.x;
    if (b < NB) {
        float sr = g_stats[b*4+0], si = g_stats[b*4+1], sq = g_stats[b*4+2];
        const float n = (float)(NC * NL);
        float var = (sq - (sr*sr + si*si)/n) / (n - 1.0f);
        g_stats[b*4+3] = rsqrtf(var);
    }
}

// Guarded float4 row load; g0 is wave-uniform (same for all lanes) -> the
// branch is uniform, no divergence. Guards only fire for edge tiles.
__device__ __forceinline__ float4 ldx(const float* __restrict__ xr, int g0)
{
    if (g0 >= 0 && g0 <= NL - 4) return *(const float4*)(xr + g0);
    float4 v;
    v.x = (g0 + 0 >= 0 && g0 + 0 < NL) ? xr[g0 + 0] : 0.0f;
    v.y = (g0 + 1 >= 0 && g0 + 1 < NL) ? xr[g0 + 1] : 0.0f;
    v.z = (g0 + 2 >= 0 && g0 + 2 < NL) ? xr[g0 + 2] : 0.0f;
    v.w = (g0 + 3 >= 0 && g0 + 3 < NL) ? xr[g0 + 3] : 0.0f;
    return v;
}

// ---------------------------------------------------------------------------
// Fused: conv (direct global->register window, x is XCD-L2-resident) + stats
// + weight (inv_std deferred to scale_out_kernel by linearity) + 256-pt FFT
// over channels + fftshift + real-part store.
// Block = one 16-wide l-tile; thread = channel. 2048 blocks; b = bid&7 pins
// each batch to one XCD (4 MB x-batch == one XCD L2).
// R5 failure fixed: no strip loop (VGPR 152->~125), no conv LDS staging
// (150->~80 b128/thread), barriers/tile 12->5.
// ---------------------------------------------------------------------------
__global__ __launch_bounds__(256) void fused_conv_fft_kernel(
    const float* __restrict__ x,
    const float* __restrict__ kre,
    const float* __restrict__ kim,
    const float* __restrict__ wmag,
    const float* __restrict__ wang,
    float* __restrict__ out,
    int out_size)
{
    __shared__ __align__(16) float4 lbuf4[NC * 9];  // 36 KB FFT workspace
    __shared__ float twr[NC], twi[NC];
    __shared__ float red[12];

    const int t = threadIdx.x;              // channel
    const int b = blockIdx.x & 7;           // batch == XCD
    const int tile = blockIdx.x >> 3;       // 0..255
    const int l0 = tile << 4;

    {
        float ang = (float)t * 0.024543692606170260f;  // 2*pi/256
        float s, c;
        sincosf(ang, &s, &c);
        twr[t] = c; twi[t] = -s;
    }
    float sw, cw;
    sincosf(wang[t], &sw, &cw);
    const float wm = wmag[t];
    const float wgr =  wm * cw;             // weight WITHOUT inv_std
    const float wgi = -wm * sw;

    const float* xrow = x + (size_t)(b * NC + t) * NL;
    const bool interleaved = (out_size >= 2 * NB * NC * NL);

    // ---- conv: 16 outputs, 65 taps, via 12-float4 ring buffer ----
    // slot s holds a float4; chunk cb uses slots (4cb..4cb+7)%12 covering
    // words l0-32+16cb .. +31; after chunks 0..2 refill slots (4cb..4cb+3)%12
    // with words l0+16+16cb. Tail tap j=64 uses slots 4..7 (words l0+32..47).
    float4 vb[12];
    #pragma unroll
    for (int i = 0; i < 12; ++i) vb[i] = ldx(xrow, l0 - 32 + 4 * i);

    float sr[16], si[16];
    #pragma unroll
    for (int i = 0; i < 16; ++i) { sr[i] = 0.0f; si[i] = 0.0f; }

    #pragma unroll
    for (int cb = 0; cb < 4; ++cb) {
        float w[32];
        #pragma unroll
        for (int q = 0; q < 8; ++q) {
            float4 v = vb[(4 * cb + q) % 12];
            w[4*q+0] = v.x; w[4*q+1] = v.y; w[4*q+2] = v.z; w[4*q+3] = v.w;
        }
        #pragma unroll
        for (int j2 = 0; j2 < 16; ++j2) {
            const float kr = kre[16 * cb + j2];   // uniform -> s_load
            const float ki = kim[16 * cb + j2];
            #pragma unroll
            for (int i = 0; i < 16; ++i) {
                sr[i] = fmaf(w[i + j2], kr, sr[i]);
                si[i] = fmaf(w[i + j2], ki, si[i]);
            }
        }
        if (cb < 3) {
            #pragma unroll
            for (int q = 0; q < 4; ++q)
                vb[(4 * cb + q) % 12] = ldx(xrow, l0 + 16 + 16 * cb + 4 * q);
        }
    }
    {   // tail tap j = 64: words l0+32..l0+47 = slots 4..7
        const float kr = kre[64];
        const float ki = kim[64];
        float w[16];
        #pragma unroll
        for (int q = 0; q < 4; ++q) {
            float4 v = vb[4 + q];
            w[4*q+0] = v.x; w[4*q+1] = v.y; w[4*q+2] = v.z; w[4*q+3] = v.w;
        }
        #pragma unroll
        for (int i = 0; i < 16; ++i) {
            sr[i] = fmaf(w[i], kr, sr[i]);
            si[i] = fmaf(w[i], ki, si[i]);
        }
    }

    // ---- stats on y = (sr, -si), un-normalized ----
    float tsr = 0.0f, tsi = 0.0f, tsq = 0.0f;
    #pragma unroll
    for (int i = 0; i < 16; ++i) {
        tsr += sr[i];
        tsi -= si[i];
        tsq = fmaf(sr[i], sr[i], tsq);
        tsq = fmaf(si[i], si[i], tsq);
    }

    // ---- weight: y' = y * (wgr + i*wgi) -> own FFT row ----
    #pragma unroll
    for (int k = 0; k < 8; ++k) {
        float4 o;
        o.x = sr[2*k]   * wgr + si[2*k]   * wgi;
        o.y = sr[2*k]   * wgi - si[2*k]   * wgr;
        o.z = sr[2*k+1] * wgr + si[2*k+1] * wgi;
        o.w = sr[2*k+1] * wgi - si[2*k+1] * wgr;
        lbuf4[t * 9 + k] = o;
    }
    __syncthreads();   // also covers twr/twi init

    // ---- 4 radix-4 DIF stages over channels (row stride 9 float4) ----
    #pragma unroll
    for (int s = 0; s < 4; ++s) {
        const int shift = 2 * s;
        const int q = 64 >> shift;
        #pragma unroll
        for (int it = 0; it < 2; ++it) {
            int task = it * 256 + t;       // 512 tasks = 64 butterflies x 8 lpairs
            int lpp = task & 7;
            int m = task >> 3;
            int j = m & (q - 1);
            int blk = m >> (6 - shift);
            int base2 = blk << (8 - shift);
            int e = j << shift;            // 3e <= 189 < 256

            int ca = base2 + j;
            float4 a0 = lbuf4[ca*9 + lpp];
            float4 a1 = lbuf4[(ca + q)*9 + lpp];
            float4 a2 = lbuf4[(ca + 2*q)*9 + lpp];
            float4 a3 = lbuf4[(ca + 3*q)*9 + lpp];

            float w1r = twr[e],   w1i = twi[e];
            float w2r = twr[2*e], w2i = twi[2*e];
            float w3r = twr[3*e], w3i = twi[3*e];

            float4 b0, b1, b2, b3;
            {
                float t0r = a0.x + a2.x, t0i = a0.y + a2.y;
                float t1r = a0.x - a2.x, t1i = a0.y - a2.y;
                float t2r = a1.x + a3.x, t2i = a1.y + a3.y;
                float t3r = a1.x - a3.x, t3i = a1.y - a3.y;
                b0.x = t0r + t2r;       b0.y = t0i + t2i;
                float b2r = t0r - t2r,  b2i = t0i - t2i;
                float b1r = t1r + t3i,  b1i = t1i - t3r;
                float b3r = t1r - t3i,  b3i = t1i + t3r;
                b1.x = b1r*w1r - b1i*w1i;  b1.y = b1r*w1i + b1i*w1r;
                b2.x = b2r*w2r - b2i*w2i;  b2.y = b2r*w2i + b2i*w2r;
                b3.x = b3r*w3r - b3i*w3i;  b3.y = b3r*w3i + b3i*w3r;
            }
            {
                float t0r = a0.z + a2.z, t0i = a0.w + a2.w;
                float t1r = a0.z - a2.z, t1i = a0.w - a2.w;
                float t2r = a1.z + a3.z, t2i = a1.w + a3.w;
                float t3r = a1.z - a3.z, t3i = a1.w - a3.w;
                b0.z = t0r + t2r;       b0.w = t0i + t2i;
                float b2r = t0r - t2r,  b2i = t0i - t2i;
                float b1r = t1r + t3i,  b1i = t1i - t3r;
                float b3r = t1r - t3i,  b3i = t1i + t3r;
                b1.z = b1r*w1r - b1i*w1i;  b1.w = b1r*w1i + b1i*w1r;
                b2.z = b2r*w2r - b2i*w2i;  b2.w = b2r*w2i + b2i*w2r;
                b3.z = b3r*w3r - b3i*w3i;  b3.w = b3r*w3i + b3i*w3r;
            }
            lbuf4[ca*9 + lpp]         = b0;
            lbuf4[(ca + q)*9 + lpp]   = b1;
            lbuf4[(ca + 2*q)*9 + lpp] = b2;
            lbuf4[(ca + 3*q)*9 + lpp] = b3;
        }
        __syncthreads();
    }

    // ---- store (un-normalized): digit-reverse + fftshift ----
    #pragma unroll
    for (int it = 0; it < 8; ++it) {
        int task = it * 256 + t;
        int lpp = task & 7;
        int pp = task >> 3;
        float4 v = lbuf4[pp*9 + lpp];
        int k = ((pp & 3) << 6) | (((pp >> 2) & 3) << 4)
              | (((pp >> 4) & 3) << 2) | ((pp >> 6) & 3);
        int cout = k ^ 128;  // fftshift
        if (interleaved) {
            size_t fi = 2 * ((size_t)(b * NC + cout) * NL + l0) + 4 * lpp;
            if (fi + 4 <= (size_t)out_size) *(float4*)(out + fi) = v;
        } else {
            size_t fi = (size_t)(b * NC + cout) * NL + l0 + 2 * lpp;
            if (fi + 2 <= (size_t)out_size) {
                float2 o2; o2.x = v.x; o2.y = v.z;
                *(float2*)(out + fi) = o2;
            }
        }
    }

    // ---- block stats -> per-batch atomics ----
    #pragma unroll
    for (int off = 32; off > 0; off >>= 1) {
        tsr += __shfl_down(tsr, off);
        tsi += __shfl_down(tsi, off);
        tsq += __shfl_down(tsq, off);
    }
    const int lane = t & 63, wv = t >> 6;
    if (lane == 0) { red[wv*3+0] = tsr; red[wv*3+1] = tsi; red[wv*3+2] = tsq; }
    __syncthreads();
    if (t == 0) {
        float a0 = 0.0f, a1 = 0.0f, a2 = 0.0f;
        for (int i = 0; i < 4; ++i) { a0 += red[i*3]; a1 += red[i*3+1]; a2 += red[i*3+2]; }
        atomicAdd(&g_stats[b*4+0], a0);
        atomicAdd(&g_stats[b*4+1], a1);
        atomicAdd(&g_stats[b*4+2], a2);
    }
}

// ---------------------------------------------------------------------------
// out *= inv_std[b]; b = flat_idx / (out_size/NB) for both layouts.
// ---------------------------------------------------------------------------
__global__ __launch_bounds__(256) void scale_out_kernel(
    float* __restrict__ out, int out_size)
{
    const int chunk = out_size >> 3;           // floats per batch (NB=8)
    const int n4 = out_size >> 2;
    float4* o4 = (float4*)out;
    for (int i4 = blockIdx.x * blockDim.x + threadIdx.x; i4 < n4;
         i4 += gridDim.x * blockDim.x) {
        int b = (i4 << 2) / chunk;
        float inv = g_stats[b*4+3];
        float4 v = o4[i4];
        v.x *= inv; v.y *= inv; v.z *= inv; v.w *= inv;
        o4[i4] = v;
    }
    int tail0 = n4 << 2;
    int ti = tail0 + blockIdx.x * blockDim.x + threadIdx.x;
    if (ti < out_size) {
        int b = ti / chunk;
        out[ti] *= g_stats[b*4+3];
    }
}

extern "C" void kernel_launch(void* const* d_in, const int* in_sizes, int n_in,
                              void* d_out, int out_size, void* d_ws, size_t ws_size,
                              hipStream_t stream)
{
    const float* x   = (const float*)d_in[0];
    const float* kre = (const float*)d_in[1];
    const float* kim = (const float*)d_in[2];
    const float* wm  = (const float*)d_in[3];
    const float* wa  = (const float*)d_in[4];
    float* out = (float*)d_out;
    (void)d_ws; (void)ws_size;

    zero_stats_kernel<<<1, 64, 0, stream>>>();
    fused_conv_fft_kernel<<<NB * (NL / 16), 256, 0, stream>>>(x, kre, kim, wm, wa,
                                                              out, out_size);
    finalize_stats_kernel<<<1, 64, 0, stream>>>();
    scale_out_kernel<<<2048, 256, 0, stream>>>(out, out_size);
}

// Round 7
// 174.342 us; speedup vs baseline: 1.4089x; 1.0390x over previous
//
#include <hip/hip_runtime.h>
#include <math.h>

#define NB 8
#define NC 256
#define NL 4096
#define NK 65

// Per-batch stats. [b][0..3] = sum_re, sum_im, sum_sq, inv_std
__device__ float g_stats[NB * 4];

__global__ void zero_stats_kernel() {
    if (threadIdx.x < NB * 4) g_stats[threadIdx.x] = 0.0f;
}

__global__ void finalize_stats_kernel()
{
    int b = threadIdx.x;
    if (b < NB) {
        float sr = g_stats[b*4+0], si = g_stats[b*4+1], sq = g_stats[b*4+2];
        const float n = (float)(NC * NL);
        float var = (sq - (sr*sr + si*si)/n) / (n - 1.0f);
        g_stats[b*4+3] = rsqrtf(var);
    }
}

__device__ __forceinline__ unsigned int bf16_rne(float f) {
    unsigned int u = __float_as_uint(f);
    u += 0x7FFFu + ((u >> 16) & 1u);
    return u >> 16;
}

// XOR swizzle on float4 index: spreads lane-stride-4 b128 reads over all 8
// bank-quads.
__device__ __forceinline__ int swz(int a) { return a ^ ((a >> 3) & 7); }

// ---------------------------------------------------------------------------
// Pass A: row-major conv (coalesced LDS staging, tap-chunked so windows stay
// in VGPRs) + per-batch stats + store UN-weighted y into ybuf (= d_out used
// as scratch). packed=1: y as bf16 pair in u32 (33.55 MB == out capacity in
// the real-output case). packed=0: y as f32 pairs (interleaved-output case,
// capacity 67 MB). Stats computed on fp32 values BEFORE quantization.
// ---------------------------------------------------------------------------
__global__ __launch_bounds__(256) void conv_pass_kernel(
    const float* __restrict__ x,
    const float* __restrict__ kre,
    const float* __restrict__ kim,
    void* ybuf, int packed)
{
    __shared__ __align__(16) float4 xs4[1040];  // words 4a-32..4a-29, swizzled
    __shared__ float red[12];

    const int t = threadIdx.x;
    const int r = blockIdx.x;               // row = b*NC + c
    const int b = r >> 8;
    const float* xrow = x + (size_t)r * NL;

    #pragma unroll
    for (int it = 0; it < 5; ++it) {
        int a = it * 256 + t;
        if (a < 1040) {
            float4 v; int g0 = 4 * a - 32;
            if (a >= 8 && a <= 1031) {
                v = *(const float4*)(xrow + g0);
            } else {
                v.x = (g0 + 0 >= 0 && g0 + 0 < NL) ? xrow[g0 + 0] : 0.0f;
                v.y = (g0 + 1 >= 0 && g0 + 1 < NL) ? xrow[g0 + 1] : 0.0f;
                v.z = (g0 + 2 >= 0 && g0 + 2 < NL) ? xrow[g0 + 2] : 0.0f;
                v.w = (g0 + 3 >= 0 && g0 + 3 < NL) ? xrow[g0 + 3] : 0.0f;
            }
            xs4[swz(a)] = v;
        }
    }
    __syncthreads();

    float sr[16], si[16];
    #pragma unroll
    for (int i = 0; i < 16; ++i) { sr[i] = 0.0f; si[i] = 0.0f; }

    const int a0 = 4 * t;
    #pragma unroll
    for (int cb = 0; cb < 4; ++cb) {
        float w[32];
        #pragma unroll
        for (int q = 0; q < 8; ++q) {
            float4 v = xs4[swz(a0 + 4 * cb + q)];
            w[4*q+0] = v.x; w[4*q+1] = v.y; w[4*q+2] = v.z; w[4*q+3] = v.w;
        }
        #pragma unroll
        for (int j2 = 0; j2 < 16; ++j2) {
            const float kr = kre[16 * cb + j2];   // uniform -> s_load
            const float ki = kim[16 * cb + j2];
            #pragma unroll
            for (int i = 0; i < 16; ++i) {
                sr[i] = fmaf(w[i + j2], kr, sr[i]);
                si[i] = fmaf(w[i + j2], ki, si[i]);
            }
        }
    }
    {   // tail tap j = 64
        float w[16];
        #pragma unroll
        for (int q = 0; q < 4; ++q) {
            float4 v = xs4[swz(a0 + 16 + q)];
            w[4*q+0] = v.x; w[4*q+1] = v.y; w[4*q+2] = v.z; w[4*q+3] = v.w;
        }
        const float kr = kre[64];
        const float ki = kim[64];
        #pragma unroll
        for (int i = 0; i < 16; ++i) {
            sr[i] = fmaf(w[i], kr, sr[i]);
            si[i] = fmaf(w[i], ki, si[i]);
        }
    }

    // ---- store y = (sr, -si), coalesced (lane-dense 64 B per thread) ----
    if (packed) {
        unsigned int* yb = (unsigned int*)ybuf + (size_t)r * NL + 16 * t;
        #pragma unroll
        for (int g = 0; g < 4; ++g) {
            uint4 o;
            o.x = bf16_rne(sr[4*g+0]) | (bf16_rne(-si[4*g+0]) << 16);
            o.y = bf16_rne(sr[4*g+1]) | (bf16_rne(-si[4*g+1]) << 16);
            o.z = bf16_rne(sr[4*g+2]) | (bf16_rne(-si[4*g+2]) << 16);
            o.w = bf16_rne(sr[4*g+3]) | (bf16_rne(-si[4*g+3]) << 16);
            *(uint4*)(yb + 4 * g) = o;
        }
    } else {
        float2* yb = (float2*)ybuf + (size_t)r * NL + 16 * t;
        #pragma unroll
        for (int i = 0; i < 16; ++i) {
            float2 o; o.x = sr[i]; o.y = -si[i];
            yb[i] = o;
        }
    }

    // ---- stats (fp32, pre-quantization) ----
    float tsr = 0.0f, tsi = 0.0f, tsq = 0.0f;
    #pragma unroll
    for (int i = 0; i < 16; ++i) {
        tsr += sr[i];
        tsi -= si[i];
        tsq = fmaf(sr[i], sr[i], tsq);
        tsq = fmaf(si[i], si[i], tsq);
    }
    #pragma unroll
    for (int off = 32; off > 0; off >>= 1) {
        tsr += __shfl_down(tsr, off);
        tsi += __shfl_down(tsi, off);
        tsq += __shfl_down(tsq, off);
    }
    const int lane = t & 63, wv = t >> 6;
    if (lane == 0) { red[wv*3+0] = tsr; red[wv*3+1] = tsi; red[wv*3+2] = tsq; }
    __syncthreads();
    if (t == 0) {
        float a0s = 0.0f, a1s = 0.0f, a2s = 0.0f;
        for (int i = 0; i < 4; ++i) { a0s += red[i*3]; a1s += red[i*3+1]; a2s += red[i*3+2]; }
        atomicAdd(&g_stats[b*4+0], a0s);
        atomicAdd(&g_stats[b*4+1], a1s);
        atomicAdd(&g_stats[b*4+2], a2s);
    }
}

// ---------------------------------------------------------------------------
// Pass B: load y (coalesced), apply inv_std*weight AT LOAD (scale pass
// eliminated by linearity), radix-4 FFT over channels, fftshift, store.
// In-place on the same buffer: each block reads & writes only its own
// (b, l-tile) byte range, all reads staged to LDS before any store.
// ---------------------------------------------------------------------------
__global__ __launch_bounds__(256) void fft_pass_kernel(
    const void* ybuf,
    const float* __restrict__ wmag,
    const float* __restrict__ wang,
    float* out, int out_size, int packed)
{
    __shared__ __align__(16) float4 lbuf4[NC * 9];  // 36 KB FFT workspace
    __shared__ float twr[NC], twi[NC], wgr[NC], wgi[NC];

    const int t = threadIdx.x;              // channel
    const int b = blockIdx.x >> 8;
    const int l0 = (blockIdx.x & 255) << 4;

    {
        float ang = (float)t * 0.024543692606170260f;  // 2*pi/256
        float s, c;
        sincosf(ang, &s, &c);
        twr[t] = c; twi[t] = -s;
    }
    {
        float sw, cw;
        sincosf(wang[t], &sw, &cw);
        const float inv = g_stats[b*4+3];
        const float wm = wmag[t];
        wgr[t] =  inv * wm * cw;
        wgi[t] = -inv * wm * sw;
    }
    __syncthreads();

    // ---- load + weight into FFT layout ----
    if (packed) {
        const uint2* g2 = (const uint2*)((const unsigned int*)ybuf
                                         + (size_t)b * NC * NL + l0);
        #pragma unroll
        for (int it = 0; it < 8; ++it) {
            int fidx = it * 256 + t;
            int rr = fidx >> 3, q = fidx & 7;
            uint2 u = g2[(size_t)rr * (NL / 2) + q];
            float re0 = __uint_as_float(u.x << 16);
            float im0 = __uint_as_float(u.x & 0xFFFF0000u);
            float re1 = __uint_as_float(u.y << 16);
            float im1 = __uint_as_float(u.y & 0xFFFF0000u);
            float wr = wgr[rr], wi = wgi[rr];
            float4 o;
            o.x = re0*wr - im0*wi;  o.y = re0*wi + im0*wr;
            o.z = re1*wr - im1*wi;  o.w = re1*wi + im1*wr;
            lbuf4[rr*9 + q] = o;
        }
    } else {
        const float4* g4 = (const float4*)((const float*)ybuf
                                           + 2 * ((size_t)b * NC * NL + l0));
        #pragma unroll
        for (int it = 0; it < 8; ++it) {
            int fidx = it * 256 + t;
            int rr = fidx >> 3, q = fidx & 7;
            float4 v = g4[(size_t)rr * (NL / 2) + q];
            float wr = wgr[rr], wi = wgi[rr];
            float4 o;
            o.x = v.x*wr - v.y*wi;  o.y = v.x*wi + v.y*wr;
            o.z = v.z*wr - v.w*wi;  o.w = v.z*wi + v.w*wr;
            lbuf4[rr*9 + q] = o;
        }
    }
    __syncthreads();

    // ---- 4 radix-4 DIF stages over channels (row stride 9 float4) ----
    #pragma unroll
    for (int s = 0; s < 4; ++s) {
        const int shift = 2 * s;
        const int q = 64 >> shift;
        #pragma unroll
        for (int it = 0; it < 2; ++it) {
            int task = it * 256 + t;       // 512 tasks = 64 butterflies x 8 lpairs
            int lpp = task & 7;
            int m = task >> 3;
            int j = m & (q - 1);
            int blk = m >> (6 - shift);
            int base2 = blk << (8 - shift);
            int e = j << shift;            // 3e <= 189 < 256

            int ca = base2 + j;
            float4 a0 = lbuf4[ca*9 + lpp];
            float4 a1 = lbuf4[(ca + q)*9 + lpp];
            float4 a2 = lbuf4[(ca + 2*q)*9 + lpp];
            float4 a3 = lbuf4[(ca + 3*q)*9 + lpp];

            float w1r = twr[e],   w1i = twi[e];
            float w2r = twr[2*e], w2i = twi[2*e];
            float w3r = twr[3*e], w3i = twi[3*e];

            float4 b0, b1, b2, b3;
            {
                float t0r = a0.x + a2.x, t0i = a0.y + a2.y;
                float t1r = a0.x - a2.x, t1i = a0.y - a2.y;
                float t2r = a1.x + a3.x, t2i = a1.y + a3.y;
                float t3r = a1.x - a3.x, t3i = a1.y - a3.y;
                b0.x = t0r + t2r;       b0.y = t0i + t2i;
                float b2r = t0r - t2r,  b2i = t0i - t2i;
                float b1r = t1r + t3i,  b1i = t1i - t3r;
                float b3r = t1r - t3i,  b3i = t1i + t3r;
                b1.x = b1r*w1r - b1i*w1i;  b1.y = b1r*w1i + b1i*w1r;
                b2.x = b2r*w2r - b2i*w2i;  b2.y = b2r*w2i + b2i*w2r;
                b3.x = b3r*w3r - b3i*w3i;  b3.y = b3r*w3i + b3i*w3r;
            }
            {
                float t0r = a0.z + a2.z, t0i = a0.w + a2.w;
                float t1r = a0.z - a2.z, t1i = a0.w - a2.w;
                float t2r = a1.z + a3.z, t2i = a1.w + a3.w;
                float t3r = a1.z - a3.z, t3i = a1.w - a3.w;
                b0.z = t0r + t2r;       b0.w = t0i + t2i;
                float b2r = t0r - t2r,  b2i = t0i - t2i;
                float b1r = t1r + t3i,  b1i = t1i - t3r;
                float b3r = t1r - t3i,  b3i = t1i + t3r;
                b1.z = b1r*w1r - b1i*w1i;  b1.w = b1r*w1i + b1i*w1r;
                b2.z = b2r*w2r - b2i*w2i;  b2.w = b2r*w2i + b2i*w2r;
                b3.z = b3r*w3r - b3i*w3i;  b3.w = b3r*w3i + b3i*w3r;
            }
            lbuf4[ca*9 + lpp]         = b0;
            lbuf4[(ca + q)*9 + lpp]   = b1;
            lbuf4[(ca + 2*q)*9 + lpp] = b2;
            lbuf4[(ca + 3*q)*9 + lpp] = b3;
        }
        __syncthreads();
    }

    // ---- store: digit-reverse + fftshift ----
    const bool interleaved = !packed;
    #pragma unroll
    for (int it = 0; it < 8; ++it) {
        int task = it * 256 + t;
        int lpp = task & 7;
        int pp = task >> 3;
        float4 v = lbuf4[pp*9 + lpp];
        int k = ((pp & 3) << 6) | (((pp >> 2) & 3) << 4)
              | (((pp >> 4) & 3) << 2) | ((pp >> 6) & 3);
        int cout = k ^ 128;  // fftshift
        if (interleaved) {
            size_t fi = 2 * ((size_t)(b * NC + cout) * NL + l0) + 4 * lpp;
            if (fi + 4 <= (size_t)out_size) *(float4*)(out + fi) = v;
        } else {
            size_t fi = (size_t)(b * NC + cout) * NL + l0 + 2 * lpp;
            if (fi + 2 <= (size_t)out_size) {
                float2 o2; o2.x = v.x; o2.y = v.z;
                *(float2*)(out + fi) = o2;
            }
        }
    }
}

extern "C" void kernel_launch(void* const* d_in, const int* in_sizes, int n_in,
                              void* d_out, int out_size, void* d_ws, size_t ws_size,
                              hipStream_t stream)
{
    const float* x   = (const float*)d_in[0];
    const float* kre = (const float*)d_in[1];
    const float* kim = (const float*)d_in[2];
    const float* wm  = (const float*)d_in[3];
    const float* wa  = (const float*)d_in[4];
    float* out = (float*)d_out;
    (void)d_ws; (void)ws_size;

    // Real-part output (out_size == B*C*L): pack y as bf16 pairs -> exactly
    // fits d_out. Interleaved complex output (2*B*C*L): store y as f32 pairs.
    const int packed = (out_size < 2 * NB * NC * NL) ? 1 : 0;

    zero_stats_kernel<<<1, 64, 0, stream>>>();
    conv_pass_kernel<<<NB * NC, 256, 0, stream>>>(x, kre, kim, d_out, packed);
    finalize_stats_kernel<<<1, 64, 0, stream>>>();
    fft_pass_kernel<<<NB * (NL / 16), 256, 0, stream>>>(d_out, wm, wa,
                                                        out, out_size, packed);
}

// Round 8
// 161.141 us; speedup vs baseline: 1.5244x; 1.0819x over previous
//
#include <hip/hip_runtime.h>
#include <math.h>

#define NB 8
#define NC 256
#define NL 4096
#define NK 65

// Per-batch stats. [b][0..3] = sum_re, sum_im, sum_sq, inv_std
__device__ float g_stats[NB * 4];

__global__ void zero_stats_kernel() {
    if (threadIdx.x < NB * 4) g_stats[threadIdx.x] = 0.0f;
}

__global__ void finalize_stats_kernel()
{
    int b = threadIdx.x;
    if (b < NB) {
        float sr = g_stats[b*4+0], si = g_stats[b*4+1], sq = g_stats[b*4+2];
        const float n = (float)(NC * NL);
        float var = (sq - (sr*sr + si*si)/n) / (n - 1.0f);
        g_stats[b*4+3] = rsqrtf(var);
    }
}

// ---------------------------------------------------------------------------
// Fused: conv (per-tap-chunk coalesced LDS staging of x, register compute)
// + pre-weight stats + weight (inv_std deferred by linearity to scale pass)
// + 256-pt radix-4 FFT over channels + fftshift + real-part store.
// This is the R4 74-us kernel + XCD swizzle (b=bid&7: one batch == 4 MB of x
// == one XCD L2, so halo re-reads between neighboring tiles hit L2 instead
// of refetching 151 MB from HBM) + deferred inv_std.
// Block = one 16-wide l-tile, thread = channel.
// ---------------------------------------------------------------------------
__global__ __launch_bounds__(256) void fused_conv_fft_kernel(
    const float* __restrict__ x,
    const float* __restrict__ kre,
    const float* __restrict__ kim,
    const float* __restrict__ wmag,
    const float* __restrict__ wang,
    float* __restrict__ out,
    int out_size)
{
    __shared__ __align__(16) float4 lbuf4[NC * 9];  // 36 KB: staging, then FFT
    __shared__ float twr[NC], twi[NC];
    __shared__ float red[12];

    const int t = threadIdx.x;              // channel
    const int b = blockIdx.x & 7;           // batch == XCD
    const int l0 = (blockIdx.x >> 3) << 4;  // tile base

    {
        float ang = (float)t * 0.024543692606170260f;  // 2*pi/256
        float s, c;
        sincosf(ang, &s, &c);
        twr[t] = c; twi[t] = -s;
    }
    float sw, cw;
    sincosf(wang[t], &sw, &cw);
    const float wm = wmag[t];
    const float wgr =  wm * cw;             // weight WITHOUT inv_std
    const float wgi = -wm * sw;

    const float* xb = x + (size_t)b * NC * NL;
    const bool interleaved = (out_size >= 2 * NB * NC * NL);

    float sr[16], si[16];
    #pragma unroll
    for (int i = 0; i < 16; ++i) { sr[i] = 0.0f; si[i] = 0.0f; }

    #pragma unroll
    for (int cb = 0; cb < 4; ++cb) {
        __syncthreads();   // prior chunk's reads / twiddle init done
        // stage 256 rows x 32 words, coalesced
        #pragma unroll
        for (int it = 0; it < 8; ++it) {
            int fidx = it * 256 + t;
            int rr = fidx >> 3, q = fidx & 7;
            int g0 = l0 + 16 * cb - 32 + 4 * q;
            const float* xr = xb + (size_t)rr * NL;
            float4 v;
            if (g0 >= 0 && g0 <= NL - 4) {
                v = *(const float4*)(xr + g0);
            } else {
                v.x = (g0 + 0 >= 0 && g0 + 0 < NL) ? xr[g0 + 0] : 0.0f;
                v.y = (g0 + 1 >= 0 && g0 + 1 < NL) ? xr[g0 + 1] : 0.0f;
                v.z = (g0 + 2 >= 0 && g0 + 2 < NL) ? xr[g0 + 2] : 0.0f;
                v.w = (g0 + 3 >= 0 && g0 + 3 < NL) ? xr[g0 + 3] : 0.0f;
            }
            lbuf4[rr * 9 + q] = v;
        }
        __syncthreads();
        float w[32];
        #pragma unroll
        for (int q = 0; q < 8; ++q) {
            float4 v = lbuf4[t * 9 + q];   // quad=(t+q)&7: even bank spread
            w[4*q+0] = v.x; w[4*q+1] = v.y; w[4*q+2] = v.z; w[4*q+3] = v.w;
        }
        #pragma unroll
        for (int j2 = 0; j2 < 16; ++j2) {
            const float kr = kre[16 * cb + j2];   // uniform -> s_load
            const float ki = kim[16 * cb + j2];
            #pragma unroll
            for (int i = 0; i < 16; ++i) {
                sr[i] = fmaf(w[i + j2], kr, sr[i]);
                si[i] = fmaf(w[i + j2], ki, si[i]);
            }
        }
    }
    // tail tap j = 64: words l0+32 .. l0+47 per row
    __syncthreads();
    #pragma unroll
    for (int it = 0; it < 4; ++it) {
        int fidx = it * 256 + t;
        int rr = fidx >> 2, q = fidx & 3;
        int g0 = l0 + 32 + 4 * q;
        const float* xr = xb + (size_t)rr * NL;
        float4 v;
        if (g0 <= NL - 4) {
            v = *(const float4*)(xr + g0);
        } else {
            v.x = (g0 + 0 < NL) ? xr[g0 + 0] : 0.0f;
            v.y = (g0 + 1 < NL) ? xr[g0 + 1] : 0.0f;
            v.z = (g0 + 2 < NL) ? xr[g0 + 2] : 0.0f;
            v.w = (g0 + 3 < NL) ? xr[g0 + 3] : 0.0f;
        }
        lbuf4[rr * 9 + q] = v;
    }
    __syncthreads();
    {
        float w[16];
        #pragma unroll
        for (int q = 0; q < 4; ++q) {
            float4 v = lbuf4[t * 9 + q];
            w[4*q+0] = v.x; w[4*q+1] = v.y; w[4*q+2] = v.z; w[4*q+3] = v.w;
        }
        const float kr = kre[64];
        const float ki = kim[64];
        #pragma unroll
        for (int i = 0; i < 16; ++i) {
            sr[i] = fmaf(w[i], kr, sr[i]);
            si[i] = fmaf(w[i], ki, si[i]);
        }
    }

    // ---- stats on y = (sr, -si), PRE-weight (un-normalized) ----
    float tsr = 0.0f, tsi = 0.0f, tsq = 0.0f;
    #pragma unroll
    for (int i = 0; i < 16; ++i) {
        tsr += sr[i];
        tsi -= si[i];
        tsq = fmaf(sr[i], sr[i], tsq);
        tsq = fmaf(si[i], si[i], tsq);
    }

    // ---- weight: y' = y * (wgr + i*wgi) -> own FFT row (no hazard: tail
    // reads above were own-row only) ----
    #pragma unroll
    for (int k = 0; k < 8; ++k) {
        float4 o;
        o.x = sr[2*k]   * wgr + si[2*k]   * wgi;
        o.y = sr[2*k]   * wgi - si[2*k]   * wgr;
        o.z = sr[2*k+1] * wgr + si[2*k+1] * wgi;
        o.w = sr[2*k+1] * wgi - si[2*k+1] * wgr;
        lbuf4[t * 9 + k] = o;
    }
    __syncthreads();

    // ---- 4 radix-4 DIF stages over channels (row stride 9 float4) ----
    #pragma unroll
    for (int s = 0; s < 4; ++s) {
        const int shift = 2 * s;
        const int q = 64 >> shift;
        #pragma unroll
        for (int it = 0; it < 2; ++it) {
            int task = it * 256 + t;       // 512 tasks = 64 butterflies x 8 lpairs
            int lpp = task & 7;
            int m = task >> 3;
            int j = m & (q - 1);
            int blk = m >> (6 - shift);
            int base2 = blk << (8 - shift);
            int e = j << shift;            // 3e <= 189 < 256

            int ca = base2 + j;
            float4 a0 = lbuf4[ca*9 + lpp];
            float4 a1 = lbuf4[(ca + q)*9 + lpp];
            float4 a2 = lbuf4[(ca + 2*q)*9 + lpp];
            float4 a3 = lbuf4[(ca + 3*q)*9 + lpp];

            float w1r = twr[e],   w1i = twi[e];
            float w2r = twr[2*e], w2i = twi[2*e];
            float w3r = twr[3*e], w3i = twi[3*e];

            float4 b0, b1, b2, b3;
            {
                float t0r = a0.x + a2.x, t0i = a0.y + a2.y;
                float t1r = a0.x - a2.x, t1i = a0.y - a2.y;
                float t2r = a1.x + a3.x, t2i = a1.y + a3.y;
                float t3r = a1.x - a3.x, t3i = a1.y - a3.y;
                b0.x = t0r + t2r;       b0.y = t0i + t2i;
                float b2r = t0r - t2r,  b2i = t0i - t2i;
                float b1r = t1r + t3i,  b1i = t1i - t3r;
                float b3r = t1r - t3i,  b3i = t1i + t3r;
                b1.x = b1r*w1r - b1i*w1i;  b1.y = b1r*w1i + b1i*w1r;
                b2.x = b2r*w2r - b2i*w2i;  b2.y = b2r*w2i + b2i*w2r;
                b3.x = b3r*w3r - b3i*w3i;  b3.y = b3r*w3i + b3i*w3r;
            }
            {
                float t0r = a0.z + a2.z, t0i = a0.w + a2.w;
                float t1r = a0.z - a2.z, t1i = a0.w - a2.w;
                float t2r = a1.z + a3.z, t2i = a1.w + a3.w;
                float t3r = a1.z - a3.z, t3i = a1.w - a3.w;
                b0.z = t0r + t2r;       b0.w = t0i + t2i;
                float b2r = t0r - t2r,  b2i = t0i - t2i;
                float b1r = t1r + t3i,  b1i = t1i - t3r;
                float b3r = t1r - t3i,  b3i = t1i + t3r;
                b1.z = b1r*w1r - b1i*w1i;  b1.w = b1r*w1i + b1i*w1r;
                b2.z = b2r*w2r - b2i*w2i;  b2.w = b2r*w2i + b2i*w2r;
                b3.z = b3r*w3r - b3i*w3i;  b3.w = b3r*w3i + b3i*w3r;
            }
            lbuf4[ca*9 + lpp]         = b0;
            lbuf4[(ca + q)*9 + lpp]   = b1;
            lbuf4[(ca + 2*q)*9 + lpp] = b2;
            lbuf4[(ca + 3*q)*9 + lpp] = b3;
        }
        __syncthreads();
    }

    // ---- store (un-normalized): digit-reverse + fftshift ----
    #pragma unroll
    for (int it = 0; it < 8; ++it) {
        int task = it * 256 + t;
        int lpp = task & 7;
        int pp = task >> 3;
        float4 v = lbuf4[pp*9 + lpp];
        int k = ((pp & 3) << 6) | (((pp >> 2) & 3) << 4)
              | (((pp >> 4) & 3) << 2) | ((pp >> 6) & 3);
        int cout = k ^ 128;  // fftshift
        if (interleaved) {
            size_t fi = 2 * ((size_t)(b * NC + cout) * NL + l0) + 4 * lpp;
            if (fi + 4 <= (size_t)out_size) *(float4*)(out + fi) = v;
        } else {
            size_t fi = (size_t)(b * NC + cout) * NL + l0 + 2 * lpp;
            if (fi + 2 <= (size_t)out_size) {
                float2 o2; o2.x = v.x; o2.y = v.z;
                *(float2*)(out + fi) = o2;
            }
        }
    }

    // ---- block stats -> per-batch atomics ----
    #pragma unroll
    for (int off = 32; off > 0; off >>= 1) {
        tsr += __shfl_down(tsr, off);
        tsi += __shfl_down(tsi, off);
        tsq += __shfl_down(tsq, off);
    }
    const int lane = t & 63, wv = t >> 6;
    if (lane == 0) { red[wv*3+0] = tsr; red[wv*3+1] = tsi; red[wv*3+2] = tsq; }
    __syncthreads();
    if (t == 0) {
        float a0 = 0.0f, a1 = 0.0f, a2 = 0.0f;
        for (int i = 0; i < 4; ++i) { a0 += red[i*3]; a1 += red[i*3+1]; a2 += red[i*3+2]; }
        atomicAdd(&g_stats[b*4+0], a0);
        atomicAdd(&g_stats[b*4+1], a1);
        atomicAdd(&g_stats[b*4+2], a2);
    }
}

// ---------------------------------------------------------------------------
// out *= inv_std[b]; b = flat_idx / (out_size/NB) for both layouts
// (out_size/NB is a power of two -> shift, no integer divide).
// ---------------------------------------------------------------------------
__global__ __launch_bounds__(256) void scale_out_kernel(
    float* __restrict__ out, int out_size)
{
    const int chunk = out_size >> 3;           // floats per batch (NB=8)
    const int n4 = out_size >> 2;
    float4* o4 = (float4*)out;
    for (int i4 = blockIdx.x * blockDim.x + threadIdx.x; i4 < n4;
         i4 += gridDim.x * blockDim.x) {
        int b = (i4 << 2) / chunk;
        float inv = g_stats[b*4+3];
        float4 v = o4[i4];
        v.x *= inv; v.y *= inv; v.z *= inv; v.w *= inv;
        o4[i4] = v;
    }
    int tail0 = n4 << 2;
    int ti = tail0 + blockIdx.x * blockDim.x + threadIdx.x;
    if (ti < out_size) {
        int b = ti / chunk;
        out[ti] *= g_stats[b*4+3];
    }
}

extern "C" void kernel_launch(void* const* d_in, const int* in_sizes, int n_in,
                              void* d_out, int out_size, void* d_ws, size_t ws_size,
                              hipStream_t stream)
{
    const float* x   = (const float*)d_in[0];
    const float* kre = (const float*)d_in[1];
    const float* kim = (const float*)d_in[2];
    const float* wm  = (const float*)d_in[3];
    const float* wa  = (const float*)d_in[4];
    float* out = (float*)d_out;
    (void)d_ws; (void)ws_size;

    zero_stats_kernel<<<1, 64, 0, stream>>>();
    fused_conv_fft_kernel<<<NB * (NL / 16), 256, 0, stream>>>(x, kre, kim, wm, wa,
                                                              out, out_size);
    finalize_stats_kernel<<<1, 64, 0, stream>>>();
    scale_out_kernel<<<2048, 256, 0, stream>>>(out, out_size);
}